// Round 8
// baseline (206.317 us; speedup 1.0000x reference)
//
#include <hip/hip_runtime.h>
#include <stdint.h>

// Problem constants (static per reference)
#define NG    256    // graphs
#define NPG   128    // nodes per graph
#define PP    8      // perturbations
#define IND   64     // input dim
#define HID   128    // hidden
#define OUTD  10     // classes

typedef short bf16x8 __attribute__((ext_vector_type(8)));
typedef float f32x4  __attribute__((ext_vector_type(4)));

static __device__ __forceinline__ unsigned short f2bf(float f) {
    unsigned int u = __float_as_uint(f);
    u += 0x7FFFu + ((u >> 16) & 1u);
    return (unsigned short)(u >> 16);
}

// pack 2 fp32 -> 2 bf16 in one dword: round-half-up (u+0x8000) + v_perm_b32.
// 3 VALU ops per 2 elements vs ~8 for the RNE emulation (R7 post-mortem:
// f2bf VALU was ~12 us/CU in local_mlp). 0.5-ulp worst case, same as RNE.
static __device__ __forceinline__ unsigned int pk2(float lo, float hi) {
    unsigned int a = __float_as_uint(lo) + 0x8000u;
    unsigned int b = __float_as_uint(hi) + 0x8000u;
    return __builtin_amdgcn_perm(b, a, 0x07060302u);  // [a.b2,a.b3,b.b2,b.b3]
}

static __device__ __forceinline__ bf16x8 cvt8f(float4 lo, float4 hi) {
    union { uint4 u; bf16x8 v; } o;
    o.u.x = pk2(lo.x, lo.y);
    o.u.y = pk2(lo.z, lo.w);
    o.u.z = pk2(hi.x, hi.y);
    o.u.w = pk2(hi.z, hi.w);
    return o.v;
}

static __device__ __forceinline__ f32x4 mfma16(bf16x8 a, bf16x8 b, f32x4 c) {
    return __builtin_amdgcn_mfma_f32_16x16x32_bf16(a, b, c, 0, 0, 0);
}

// ws layout:
//   shorts [0)       W1t  128x64   (Wt[out][in])
//   shorts [8192)    W2t  128x128
//   shorts [24576)   Wg1t 128x128
//   shorts [40960)   Wg2t 128x128
//   shorts [57344)   Wb1t 128x128
//   shorts [73728)   Wb2t 128x128
//   shorts [90112)   agg  32768x128 bf16
#define AGG_OFF   90112

// ---------------------------------------------------------------------------
// Kernel 0: weight convert+transpose (coalesced writes; src stays in L2)
// ---------------------------------------------------------------------------
__global__ void prep_weights(const float* __restrict__ Wl1, const float* __restrict__ Wl2,
                             const float* __restrict__ Wg1, const float* __restrict__ Wg2,
                             const float* __restrict__ Wb1, const float* __restrict__ Wb2,
                             unsigned short* __restrict__ ws) {
    int e = blockIdx.x * blockDim.x + threadIdx.x;
    if (e < 8192) {
        int n = e >> 6, k = e & 63;
        ws[e] = f2bf(Wl1[k * HID + n]);
        return;
    }
    int e2 = e - 8192;
    int m = e2 >> 14;
    int idx = e2 & 16383;
    int n = idx >> 7, k = idx & 127;
    const float* src;
    if      (m == 0) src = Wl2;
    else if (m == 1) src = Wg1;
    else if (m == 2) src = Wg2;
    else if (m == 3) src = Wb1;
    else             src = Wb2;
    ws[8192 + m * 16384 + idx] = f2bf(src[k * HID + n]);
}

#define LSTR 136   // bf16 LDS row stride (272 B): 2-way bank aliasing only (free)

// ---------------------------------------------------------------------------
// Kernel 1 (phase A): block = (g, 16-node tile). 2048 blocks x 256 threads.
// x fragments loaded DIRECTLY global->regs with 1-deep prefetch (no xbuf, no
// staging barriers; loads are register-only so they pipeline freely across
// the h1 barriers). Only LDS use is the 8.7 KB double-buffered h1.
// __launch_bounds__(256,4): 128-VGPR budget (R5: tighter bound caused spills).
// ---------------------------------------------------------------------------
__global__ __launch_bounds__(256, 4) void local_mlp(
    const float* __restrict__ x,
    const unsigned short* __restrict__ wt,
    const float* __restrict__ bl1, const float* __restrict__ bl2,
    unsigned short* __restrict__ aggbuf)
{
    __shared__ unsigned short h1buf[2][16 * LSTR];     // 8704 B

    const int g    = blockIdx.x >> 3;
    const int nt   = blockIdx.x & 7;
    const int tid  = threadIdx.x;
    const int wave = tid >> 6;
    const int lane = tid & 63;
    const int q    = lane >> 4;
    const int r    = lane & 15;
    const int ot0  = wave * 2;

    // this lane's x address: row (g,nt,r), columns q*8.. ; per-p offset 128*IND
    const float* xg = x + ((size_t)g * 1024 + nt * 16 + r) * IND + q * 8;

    // weight fragments in registers
    bf16x8 w1f[2][2];
#pragma unroll
    for (int t = 0; t < 2; ++t)
#pragma unroll
        for (int ks = 0; ks < 2; ++ks)
            w1f[t][ks] = *(const bf16x8*)(wt + ((ot0 + t) * 16 + r) * 64 + ks * 32 + q * 8);

    const unsigned short* w2t = wt + 8192;
    bf16x8 w2f[2][4];
#pragma unroll
    for (int t = 0; t < 2; ++t)
#pragma unroll
        for (int ks = 0; ks < 4; ++ks)
            w2f[t][ks] = *(const bf16x8*)(w2t + ((ot0 + t) * 16 + r) * 128 + ks * 32 + q * 8);

    float4 b1s[2], b2s[2];
#pragma unroll
    for (int t = 0; t < 2; ++t) {
        int ob = (ot0 + t) * 16 + q * 4;
        b1s[t] = *(const float4*)(bl1 + ob);
        b2s[t] = *(const float4*)(bl2 + ob);
    }

    f32x4 agg[2];
    agg[0] = (f32x4){0.f, 0.f, 0.f, 0.f};
    agg[1] = (f32x4){0.f, 0.f, 0.f, 0.f};

    // prefetch p=0 fragments (ks stride = 32 floats)
    float4 rw[2][2];
    rw[0][0] = *(const float4*)(xg);
    rw[0][1] = *(const float4*)(xg + 4);
    rw[1][0] = *(const float4*)(xg + 32);
    rw[1][1] = *(const float4*)(xg + 36);

#pragma unroll
    for (int p = 0; p < PP; ++p) {
        unsigned short* h1 = h1buf[p & 1];

        float4 c00 = rw[0][0], c01 = rw[0][1], c10 = rw[1][0], c11 = rw[1][1];
        if (p < PP - 1) {
            const float* xn = xg + (size_t)(p + 1) * 128 * IND;
            rw[0][0] = *(const float4*)(xn);
            rw[0][1] = *(const float4*)(xn + 4);
            rw[1][0] = *(const float4*)(xn + 32);
            rw[1][1] = *(const float4*)(xn + 36);
        }

        // layer 1 (K=64)
        bf16x8 xf0 = cvt8f(c00, c01);
        bf16x8 xf1 = cvt8f(c10, c11);
        f32x4 acc[2];
        acc[0] = (f32x4){0.f, 0.f, 0.f, 0.f};
        acc[1] = (f32x4){0.f, 0.f, 0.f, 0.f};
        acc[0] = mfma16(w1f[0][0], xf0, acc[0]);
        acc[1] = mfma16(w1f[1][0], xf0, acc[1]);
        acc[0] = mfma16(w1f[0][1], xf1, acc[0]);
        acc[1] = mfma16(w1f[1][1], xf1, acc[1]);

#pragma unroll
        for (int t = 0; t < 2; ++t) {
            int ob = (ot0 + t) * 16 + q * 4;
            uint2 v;
            v.x = pk2(fmaxf(acc[t][0] + b1s[t].x, 0.f), fmaxf(acc[t][1] + b1s[t].y, 0.f));
            v.y = pk2(fmaxf(acc[t][2] + b1s[t].z, 0.f), fmaxf(acc[t][3] + b1s[t].w, 0.f));
            *(uint2*)(h1 + r * LSTR + ob) = v;
        }
        __syncthreads();   // h1 visible (double buffer -> one barrier per p)

        // layer 2 (K=128), relu-accumulate into agg
        f32x4 acc2[2];
        acc2[0] = (f32x4){0.f, 0.f, 0.f, 0.f};
        acc2[1] = (f32x4){0.f, 0.f, 0.f, 0.f};
#pragma unroll
        for (int ks = 0; ks < 4; ++ks) {
            bf16x8 hf = *(const bf16x8*)(h1 + r * LSTR + ks * 32 + q * 8);
            acc2[0] = mfma16(w2f[0][ks], hf, acc2[0]);
            acc2[1] = mfma16(w2f[1][ks], hf, acc2[1]);
        }
#pragma unroll
        for (int t = 0; t < 2; ++t) {
            agg[t][0] += fmaxf(acc2[t][0] + b2s[t].x, 0.f);
            agg[t][1] += fmaxf(acc2[t][1] + b2s[t].y, 0.f);
            agg[t][2] += fmaxf(acc2[t][2] + b2s[t].z, 0.f);
            agg[t][3] += fmaxf(acc2[t][3] + b2s[t].w, 0.f);
        }
    }

    // stage agg (bf16) in h1buf[0] (p=7 barrier protects buf0's last reads)
#pragma unroll
    for (int t = 0; t < 2; ++t) {
        int ob = (ot0 + t) * 16 + q * 4;
        uint2 v;
        v.x = pk2(agg[t][0], agg[t][1]);
        v.y = pk2(agg[t][2], agg[t][3]);
        *(uint2*)(h1buf[0] + r * LSTR + ob) = v;
    }
    __syncthreads();

    // coalesced writeback: 256 threads x 16 B = the full 4 KB tile
    {
        int row = tid >> 4, c8 = (tid & 15) * 8;
        bf16x8 v = *(const bf16x8*)(h1buf[0] + row * LSTR + c8);
        *(bf16x8*)(aggbuf + ((size_t)(g * NPG + nt * 16 + row)) * HID + c8) = v;
    }
}

// ---------------------------------------------------------------------------
// Kernel 2: full-graph fused global phase. 256 blocks x 512 threads (8 waves).
// 4x (Linear+ReLU) on [128 nodes][128] IN-PLACE in one LDS buffer,
// wave-exclusive-column pool (no atomics/fences, R4 lesson), then decoder +
// log_softmax in the same block.
// ---------------------------------------------------------------------------
__global__ __launch_bounds__(512, 2) void global_full(
    const unsigned short* __restrict__ wt,
    const unsigned short* __restrict__ aggbuf,
    const float* __restrict__ bg1, const float* __restrict__ bg2,
    const float* __restrict__ bb1, const float* __restrict__ bb2,
    const float* __restrict__ Wd1, const float* __restrict__ bd1,
    const float* __restrict__ Wd2, const float* __restrict__ bd2,
    float* __restrict__ out)
{
    __shared__ unsigned short buf[128 * LSTR];   // 34816 B, reused in-place
    __shared__ float pool2[2][HID];
    __shared__ float pooled[HID];
    __shared__ float dz[64];
    __shared__ float dzz[OUTD];

    const int g    = blockIdx.x;
    const int tid  = threadIdx.x;
    const int wave = tid >> 6;
    const int lane = tid & 63;
    const int q    = lane >> 4;
    const int r    = lane & 15;
    const int ot0  = (wave & 3) * 2;   // out-tiles ot0, ot0+1
    const int b    = wave >> 2;        // row half
    const int rt0  = b * 4;            // row-tiles rt0..rt0+3

    // stage this graph's 128 agg rows (32 KB), coalesced 16 B chunks
    const unsigned short* ag = aggbuf + (size_t)g * NPG * HID;
#pragma unroll
    for (int it = 0; it < 4; ++it) {
        int c = tid + it * 512;
        int row = c >> 4, c8 = (c & 15) * 8;
        *(bf16x8*)(buf + row * LSTR + c8) = *(const bf16x8*)(ag + (size_t)row * HID + c8);
    }
    __syncthreads();

#pragma unroll
    for (int l = 0; l < 4; ++l) {
        const unsigned short* wl = wt + 24576 + l * 16384;
        const float* bl = (l == 0) ? bg1 : (l == 1) ? bg2 : (l == 2) ? bb1 : bb2;

        bf16x8 wf[2][4];
#pragma unroll
        for (int t = 0; t < 2; ++t)
#pragma unroll
            for (int ks = 0; ks < 4; ++ks)
                wf[t][ks] = *(const bf16x8*)(wl + ((ot0 + t) * 16 + r) * 128 + ks * 32 + q * 8);

        f32x4 acc[2][4];
#pragma unroll
        for (int t = 0; t < 2; ++t)
#pragma unroll
            for (int j = 0; j < 4; ++j)
                acc[t][j] = (f32x4){0.f, 0.f, 0.f, 0.f};

#pragma unroll
        for (int ks = 0; ks < 4; ++ks) {
#pragma unroll
            for (int j = 0; j < 4; ++j) {
                int row = (rt0 + j) * 16 + r;
                bf16x8 xf = *(const bf16x8*)(buf + row * LSTR + ks * 32 + q * 8);
                acc[0][j] = mfma16(wf[0][ks], xf, acc[0][j]);
                acc[1][j] = mfma16(wf[1][ks], xf, acc[1][j]);
            }
        }

        if (l < 3) {
            __syncthreads();   // everyone done reading buf for this layer
#pragma unroll
            for (int t = 0; t < 2; ++t) {
                int ob = (ot0 + t) * 16 + q * 4;
                float4 bs = *(const float4*)(bl + ob);
#pragma unroll
                for (int j = 0; j < 4; ++j) {
                    int row = (rt0 + j) * 16 + r;
                    uint2 v;
                    v.x = pk2(fmaxf(acc[t][j][0] + bs.x, 0.f), fmaxf(acc[t][j][1] + bs.y, 0.f));
                    v.y = pk2(fmaxf(acc[t][j][2] + bs.z, 0.f), fmaxf(acc[t][j][3] + bs.w, 0.f));
                    *(uint2*)(buf + row * LSTR + ob) = v;   // in-place
                }
            }
            __syncthreads();   // new layer data visible
        } else {
            // final layer: bias+relu fp32, pool this wave's 64 rows
            float s[2][4];
#pragma unroll
            for (int t = 0; t < 2; ++t) {
                int ob = (ot0 + t) * 16 + q * 4;
                float4 bs = *(const float4*)(bl + ob);
                s[t][0] = s[t][1] = s[t][2] = s[t][3] = 0.f;
#pragma unroll
                for (int j = 0; j < 4; ++j) {
                    s[t][0] += fmaxf(acc[t][j][0] + bs.x, 0.f);
                    s[t][1] += fmaxf(acc[t][j][1] + bs.y, 0.f);
                    s[t][2] += fmaxf(acc[t][j][2] + bs.z, 0.f);
                    s[t][3] += fmaxf(acc[t][j][3] + bs.w, 0.f);
                }
            }
#pragma unroll
            for (int m = 1; m < 16; m <<= 1) {
#pragma unroll
                for (int t = 0; t < 2; ++t)
#pragma unroll
                    for (int i = 0; i < 4; ++i)
                        s[t][i] += __shfl_xor(s[t][i], m, 64);
            }
            if (r == 0) {
#pragma unroll
                for (int t = 0; t < 2; ++t)
#pragma unroll
                    for (int i = 0; i < 4; ++i)
                        pool2[b][(ot0 + t) * 16 + q * 4 + i] = s[t][i];  // exclusive slot
            }
        }
    }
    __syncthreads();

    // ---- decoder + log_softmax ----
    if (tid < HID) pooled[tid] = pool2[0][tid] + pool2[1][tid];
    __syncthreads();
    if (tid < 64) {
        float a0 = bd1[tid], a1 = 0.f, a2 = 0.f, a3 = 0.f;
#pragma unroll
        for (int k = 0; k < 128; k += 4) {
            a0 += pooled[k]     * Wd1[(k)     * 64 + tid];
            a1 += pooled[k + 1] * Wd1[(k + 1) * 64 + tid];
            a2 += pooled[k + 2] * Wd1[(k + 2) * 64 + tid];
            a3 += pooled[k + 3] * Wd1[(k + 3) * 64 + tid];
        }
        dz[tid] = fmaxf((a0 + a1) + (a2 + a3), 0.f);
    }
    __syncthreads();
    if (tid < OUTD) {
        float b0 = bd2[tid], b1 = 0.f;
#pragma unroll
        for (int k = 0; k < 64; k += 2) {
            b0 += dz[k]     * Wd2[(k)     * OUTD + tid];
            b1 += dz[k + 1] * Wd2[(k + 1) * OUTD + tid];
        }
        dzz[tid] = b0 + b1;
    }
    __syncthreads();
    if (tid == 0) {
        float m = -1e30f;
#pragma unroll
        for (int j = 0; j < OUTD; ++j) m = fmaxf(m, dzz[j]);
        float ssum = 0.f;
#pragma unroll
        for (int j = 0; j < OUTD; ++j) ssum += expf(dzz[j] - m);
        float ls = logf(ssum);
#pragma unroll
        for (int j = 0; j < OUTD; ++j) out[g * OUTD + j] = dzz[j] - m - ls;
    }
}

extern "C" void kernel_launch(void* const* d_in, const int* in_sizes, int n_in,
                              void* d_out, int out_size, void* d_ws, size_t ws_size,
                              hipStream_t stream) {
    const float* x   = (const float*)d_in[0];
    // d_in[1] = ptr (unused; structure is static)
    const float* Wl1 = (const float*)d_in[2];
    const float* bl1 = (const float*)d_in[3];
    const float* Wl2 = (const float*)d_in[4];
    const float* bl2 = (const float*)d_in[5];
    const float* Wg1 = (const float*)d_in[6];
    const float* bg1 = (const float*)d_in[7];
    const float* Wg2 = (const float*)d_in[8];
    const float* bg2 = (const float*)d_in[9];
    const float* Wb1 = (const float*)d_in[10];
    const float* bb1 = (const float*)d_in[11];
    const float* Wb2 = (const float*)d_in[12];
    const float* bb2 = (const float*)d_in[13];
    const float* Wd1 = (const float*)d_in[14];
    const float* bd1 = (const float*)d_in[15];
    const float* Wd2 = (const float*)d_in[16];
    const float* bd2 = (const float*)d_in[17];

    unsigned short* ws  = (unsigned short*)d_ws;
    unsigned short* agg = ws + AGG_OFF;

    prep_weights<<<352, 256, 0, stream>>>(Wl1, Wl2, Wg1, Wg2, Wb1, Wb2, ws);
    local_mlp<<<NG * 8, 256, 0, stream>>>(x, ws, bl1, bl2, agg);
    global_full<<<NG, 512, 0, stream>>>(ws, agg, bg1, bg2, bb1, bb2,
                                        Wd1, bd1, Wd2, bd2, (float*)d_out);
}